// Round 2
// baseline (244.451 us; speedup 1.0000x reference)
//
#include <hip/hip_runtime.h>

// Problem constants
#define B_TOT   16384
#define N_CAP   32
#define J_CAP   16
#define I_DIM   8
#define D_DIM   16

#define NTH     512          // threads per block = (n 0..31) x (z 0..15)
#define NBLK    512          // grid
#define BPB     (B_TOT/NBLK) // 32 b per block
#define CHUNK   4            // b per chunk (u kept in regs across phases)
#define NCHUNK  (BPB/CHUNK)  // 8

// DPP-fused exchange-add: v + value_from(lane ^ k) for k in {1,2,8}
// xor1: quad_perm [1,0,3,2] = 0xB1 ; xor2: quad_perm [2,3,0,1] = 0x4E ;
// xor8: row_ror:8 = 0x128 (rotate by 8 within 16-lane row == lane^8)
template<int CTRL>
__device__ __forceinline__ float dpp_xadd(float v) {
    int m = __builtin_amdgcn_update_dpp(0, __float_as_int(v), CTRL, 0xF, 0xF, true);
    return v + __int_as_float(m);
}
// xor4 via ds_swizzle (BitMode: xor_mask=4, and_mask=0x1F): offset 0x101F
__device__ __forceinline__ float swz_xor4(float v) {
    return __int_as_float(__builtin_amdgcn_ds_swizzle(__float_as_int(v), 0x101F));
}

__global__ __launch_bounds__(NTH, 2)
void caps_v2(const float* __restrict__ X,     // (B, J, I)
             const float* __restrict__ Wg,    // (N, J, I, D)
             const float* __restrict__ Bias,  // (N, J, 1)
             float* __restrict__ Out)         // (B, N, D)
{
    // logits/c buffer: [cb][n*20 + j]; n-stride 20 (bank-spread, 16B-aligned),
    // b-stride 648 (=> +8 banks per b, 2-way max at softmax -> free)
    __shared__ __align__(16) float sL[CHUNK * 648];

    const int t    = threadIdx.x;
    const int z    = t & 15;      // output-capsule dim slice
    const int n    = t >> 4;      // 0..31 output capsule
    const int wave = t >> 6;      // 0..7

    // ---- W[n, j, i, z] -> 128 VGPRs (once per block; L2-hot) ----
    float Wr[16][8];
    {
        const float* wp = Wg + (size_t)n * 2048 + z;   // strides: j:128, i:16
        #pragma unroll
        for (int j = 0; j < 16; ++j)
            #pragma unroll
            for (int i = 0; i < 8; ++i)
                Wr[j][i] = wp[(j * 8 + i) * 16];
    }

    const int b0 = blockIdx.x * BPB;

    #pragma unroll 1
    for (int ch = 0; ch < NCHUNK; ++ch) {
        __syncthreads();   // WAR: prior chunk's phase-2 reads of sL complete
        float u[CHUNK][16];

        // ================= phase 1: u + logits =================
        #pragma unroll
        for (int cb = 0; cb < CHUNK; ++cb) {
            const int b = b0 + ch * CHUNK + cb;
            const float* xb = X + (size_t)b * 128;   // wave-uniform -> SMEM

            // u[j] = sum_i x[b,j,i] * W[n,j,i,z]   (128 FMA, SGPR x VGPR)
            #pragma unroll
            for (int j = 0; j < 16; ++j) {
                float acc = 0.f;
                #pragma unroll
                for (int i = 0; i < 8; ++i)
                    acc = fmaf(xb[j * 8 + i], Wr[j][i], acc);
                u[cb][j] = acc;
            }

            // usum[z] = sum_j u[j]  (in-thread)
            float us = 0.f;
            #pragma unroll
            for (int j = 0; j < 16; ++j) us += u[cb][j];

            // partial logit contributions for this z: v[j] = u[j] * usum[z]
            float v[16];
            #pragma unroll
            for (int j = 0; j < 16; ++j) v[j] = u[cb][j] * us;

            // reduce-scatter over the 16 z-lanes; lane z ends with logit[j=z]
            // stage xor8: keep j with bit3(j)==bit3(z)
            float s8[16];
            #pragma unroll
            for (int k = 0; k < 16; ++k) s8[k] = dpp_xadd<0x128>(v[k]);
            float a8[8];
            #pragma unroll
            for (int k = 0; k < 8; ++k) a8[k] = (z & 8) ? s8[k + 8] : s8[k];
            // stage xor2: keep bit1(j)==bit1(z); bit1(j of a8[k]) = bit1(k)
            float s2[8];
            #pragma unroll
            for (int k = 0; k < 8; ++k) s2[k] = dpp_xadd<0x4E>(a8[k]);
            float a2[4];
            a2[0] = (z & 2) ? s2[2] : s2[0];
            a2[1] = (z & 2) ? s2[3] : s2[1];
            a2[2] = (z & 2) ? s2[6] : s2[4];
            a2[3] = (z & 2) ? s2[7] : s2[5];
            // stage xor1: keep bit0(j)==bit0(z); bit0(j of a2[m]) = m&1
            float s1[4];
            #pragma unroll
            for (int k = 0; k < 4; ++k) s1[k] = dpp_xadd<0xB1>(a2[k]);
            float a1[2];
            a1[0] = (z & 1) ? s1[1] : s1[0];
            a1[1] = (z & 1) ? s1[3] : s1[2];
            // stage xor4 (swizzle): keep bit2(j)==bit2(z); bit2(j of a1[k]) = k
            float f0 = a1[0] + swz_xor4(a1[0]);
            float f1 = a1[1] + swz_xor4(a1[1]);
            float logit = ((z & 4) ? f1 : f0) * 0.25f;   // /sqrt(D)

            sL[cb * 648 + n * 20 + z] = logit;           // true j == z
        }
        __syncthreads();

        // ================= softmax over n (one wave, rotating) =================
        if (wave == (ch & 7)) {
            const int lt = t & 63;
            const int cb = lt >> 4, j = lt & 15;
            float l[32];
            #pragma unroll
            for (int nn = 0; nn < 32; ++nn) l[nn] = sL[cb * 648 + nn * 20 + j];
            float m = l[0];
            #pragma unroll
            for (int nn = 1; nn < 32; ++nn) m = fmaxf(m, l[nn]);
            float Zs = 0.f;
            #pragma unroll
            for (int nn = 0; nn < 32; ++nn) { l[nn] = __expf(l[nn] - m); Zs += l[nn]; }
            const float inv = 1.0f / Zs;
            #pragma unroll
            for (int nn = 0; nn < 32; ++nn)
                sL[cb * 648 + nn * 20 + j] = fmaf(l[nn], inv, Bias[nn * 16 + j]);
        }
        __syncthreads();

        // ================= phase 2: s[b,n,z] = sum_j c[b,n,j] * u[j] =================
        #pragma unroll
        for (int cb = 0; cb < CHUNK; ++cb) {
            const int b = b0 + ch * CHUNK + cb;
            const float4* cp = reinterpret_cast<const float4*>(&sL[cb * 648 + n * 20]);
            float4 c0 = cp[0], c1 = cp[1], c2 = cp[2], c3 = cp[3];
            float s = 0.f;
            s = fmaf(c0.x, u[cb][0],  s);
            s = fmaf(c0.y, u[cb][1],  s);
            s = fmaf(c0.z, u[cb][2],  s);
            s = fmaf(c0.w, u[cb][3],  s);
            s = fmaf(c1.x, u[cb][4],  s);
            s = fmaf(c1.y, u[cb][5],  s);
            s = fmaf(c1.z, u[cb][6],  s);
            s = fmaf(c1.w, u[cb][7],  s);
            s = fmaf(c2.x, u[cb][8],  s);
            s = fmaf(c2.y, u[cb][9],  s);
            s = fmaf(c2.z, u[cb][10], s);
            s = fmaf(c2.w, u[cb][11], s);
            s = fmaf(c3.x, u[cb][12], s);
            s = fmaf(c3.y, u[cb][13], s);
            s = fmaf(c3.z, u[cb][14], s);
            s = fmaf(c3.w, u[cb][15], s);
            Out[(size_t)b * 512 + n * 16 + z] = s;
        }
    }
}

extern "C" void kernel_launch(void* const* d_in, const int* in_sizes, int n_in,
                              void* d_out, int out_size, void* d_ws, size_t ws_size,
                              hipStream_t stream) {
    const float* X  = (const float*)d_in[0];   // (16384, 16, 8)
    const float* W  = (const float*)d_in[1];   // (32, 16, 8, 16)
    const float* Bi = (const float*)d_in[2];   // (32, 16, 1)
    float* Out = (float*)d_out;                // (16384, 32, 16)

    caps_v2<<<NBLK, NTH, 0, stream>>>(X, W, Bi, Out);
}

// Round 3
// 220.360 us; speedup vs baseline: 1.1093x; 1.1093x over previous
//
#include <hip/hip_runtime.h>

// Problem constants (fixed by the reference)
#define B_TOT   16384
#define N_CAP   32
#define J_CAP   16
#define I_DIM   8
#define D_DIM   16

#define NTH     512          // (n 0..31) x (j 0..15); j = low 4 lane bits
#define NBLK    512
#define BPB     (B_TOT/NBLK) // 32 b per block
#define CHUNK   2            // b per chunk; u lives in regs across softmax
#define NCHUNK  (BPB/CHUNK)  // 16

// DPP exchange-add / exchange-max.
// quad_perm xor1 = 0xB1, quad_perm xor2 = 0x4E,
// row_ror:1/2/4/8 = 0x121/0x122/0x124/0x128 (16-lane rows; ror:8 == xor8)
template<int CTRL>
__device__ __forceinline__ float dpp_xadd(float v) {
    int m = __builtin_amdgcn_update_dpp(0, __float_as_int(v), CTRL, 0xF, 0xF, true);
    return v + __int_as_float(m);
}
template<int CTRL>
__device__ __forceinline__ float dpp_xmax(float v) {
    int m = __builtin_amdgcn_update_dpp(0, __float_as_int(v), CTRL, 0xF, 0xF, true);
    return fmaxf(v, __int_as_float(m));
}
// xor4 within 16-lane group via ds_swizzle (BitMode xor_mask=4, and_mask=0x1F)
__device__ __forceinline__ float swz_xor4(float v) {
    return __int_as_float(__builtin_amdgcn_ds_swizzle(__float_as_int(v), 0x101F));
}

__global__ __launch_bounds__(NTH, 2)
void caps_v3(const float* __restrict__ X,     // (B, J, I)
             const float* __restrict__ Wg,    // (N, J, I, D)
             const float* __restrict__ Bias,  // (N, J, 1)
             float* __restrict__ Out)         // (B, N, D)
{
    // logits/c, double-buffered by chunk parity: [par][cb*544 + n*17 + j]
    __shared__ float sL[2][CHUNK * 544];

    const int t = threadIdx.x;
    const int j = t & 15;

    // ---- W[n,j,:,:] -> 128 VGPRs; t*128 is contiguous & coalesced ----
    float Wr[8][16];
    {
        const float4* wp = reinterpret_cast<const float4*>(Wg + (size_t)t * 128);
        #pragma unroll
        for (int i = 0; i < 8; ++i)
            #pragma unroll
            for (int q = 0; q < 4; ++q) {
                float4 v = wp[i * 4 + q];
                Wr[i][q*4+0] = v.x; Wr[i][q*4+1] = v.y;
                Wr[i][q*4+2] = v.z; Wr[i][q*4+3] = v.w;
            }
    }

    // softmax role (threads 0..127): (cb, j, n-quarter)
    const int sm_cb = t >> 6, sm_j = (t >> 2) & 15, sm_nq = t & 3;
    float biasr[8];
    if (t < 128) {
        #pragma unroll
        for (int k = 0; k < 8; ++k)
            biasr[k] = Bias[(sm_nq * 8 + k) * 16 + sm_j];
    }

    const int bblk = blockIdx.x * BPB;

    #pragma unroll 1
    for (int ch = 0; ch < NCHUNK; ++ch) {
        float* Ls = sL[ch & 1];
        const int b0 = bblk + ch * CHUNK;
        float u[CHUNK][16];

        // ============ phase 1: u (in regs) + logits ============
        #pragma unroll
        for (int cb = 0; cb < CHUNK; ++cb) {
            const float4* xp = reinterpret_cast<const float4*>(
                X + (size_t)(b0 + cb) * 128 + j * 8);
            float4 xa = xp[0], xb = xp[1];
            float x[8] = {xa.x, xa.y, xa.z, xa.w, xb.x, xb.y, xb.z, xb.w};

            #pragma unroll
            for (int z = 0; z < 16; ++z) u[cb][z] = x[0] * Wr[0][z];
            #pragma unroll
            for (int i = 1; i < 8; ++i)
                #pragma unroll
                for (int z = 0; z < 16; ++z)
                    u[cb][z] = fmaf(x[i], Wr[i][z], u[cb][z]);

            // usum[b,n,z]: allreduce over the 16 j-lanes (rotate-adds)
            float us[16];
            #pragma unroll
            for (int z = 0; z < 16; ++z) us[z] = dpp_xadd<0x128>(u[cb][z]);
            #pragma unroll
            for (int z = 0; z < 16; ++z) us[z] = dpp_xadd<0x124>(us[z]);
            #pragma unroll
            for (int z = 0; z < 16; ++z) us[z] = dpp_xadd<0x122>(us[z]);
            #pragma unroll
            for (int z = 0; z < 16; ++z) us[z] = dpp_xadd<0x121>(us[z]);

            float lg = 0.f;
            #pragma unroll
            for (int z = 0; z < 16; ++z) lg = fmaf(u[cb][z], us[z], lg);
            Ls[cb * 544 + (t >> 4) * 17 + j] = lg * 0.25f;   // /sqrt(D)
        }
        __syncthreads();

        // ============ softmax over n (2 waves) ============
        if (t < 128) {
            float* Lb = Ls + sm_cb * 544;
            float l[8];
            #pragma unroll
            for (int k = 0; k < 8; ++k) l[k] = Lb[(sm_nq * 8 + k) * 17 + sm_j];
            float m = l[0];
            #pragma unroll
            for (int k = 1; k < 8; ++k) m = fmaxf(m, l[k]);
            m = dpp_xmax<0xB1>(m);            // allreduce max over the 4 nq lanes
            m = dpp_xmax<0x4E>(m);
            float e[8], Z = 0.f;
            #pragma unroll
            for (int k = 0; k < 8; ++k) { e[k] = __expf(l[k] - m); Z += e[k]; }
            Z = dpp_xadd<0xB1>(Z);
            Z = dpp_xadd<0x4E>(Z);
            const float inv = __builtin_amdgcn_rcpf(Z);
            #pragma unroll
            for (int k = 0; k < 8; ++k)
                Lb[(sm_nq * 8 + k) * 17 + sm_j] = fmaf(e[k], inv, biasr[k]);
        }
        __syncthreads();

        // ============ phase 2: s[b,n,z] = sum_j c * u ============
        #pragma unroll
        for (int cb = 0; cb < CHUNK; ++cb) {
            const float c = Ls[cb * 544 + (t >> 4) * 17 + j];
            float p[16];
            #pragma unroll
            for (int z = 0; z < 16; ++z) p[z] = c * u[cb][z];

            // reduce-scatter over 16 j-lanes; lane j exits with s[z=j]
            float s8[16];
            #pragma unroll
            for (int k = 0; k < 16; ++k) s8[k] = dpp_xadd<0x128>(p[k]);
            float a8[8];
            #pragma unroll
            for (int k = 0; k < 8; ++k) a8[k] = (j & 8) ? s8[k + 8] : s8[k];
            float s2[8];
            #pragma unroll
            for (int k = 0; k < 8; ++k) s2[k] = dpp_xadd<0x4E>(a8[k]);
            float a2[4];
            a2[0] = (j & 2) ? s2[2] : s2[0];
            a2[1] = (j & 2) ? s2[3] : s2[1];
            a2[2] = (j & 2) ? s2[6] : s2[4];
            a2[3] = (j & 2) ? s2[7] : s2[5];
            float s1[4];
            #pragma unroll
            for (int k = 0; k < 4; ++k) s1[k] = dpp_xadd<0xB1>(a2[k]);
            float a1[2];
            a1[0] = (j & 1) ? s1[1] : s1[0];
            a1[1] = (j & 1) ? s1[3] : s1[2];
            float f0 = a1[0] + swz_xor4(a1[0]);
            float f1 = a1[1] + swz_xor4(a1[1]);
            float s = (j & 4) ? f1 : f0;

            Out[(size_t)(b0 + cb) * 512 + t] = s;   // b*512 + n*16 + z, coalesced
        }
    }
}

extern "C" void kernel_launch(void* const* d_in, const int* in_sizes, int n_in,
                              void* d_out, int out_size, void* d_ws, size_t ws_size,
                              hipStream_t stream) {
    const float* X  = (const float*)d_in[0];   // (16384, 16, 8)
    const float* W  = (const float*)d_in[1];   // (32, 16, 8, 16)
    const float* Bi = (const float*)d_in[2];   // (32, 16, 1)
    float* Out = (float*)d_out;                // (16384, 32, 16)

    caps_v3<<<NBLK, NTH, 0, stream>>>(X, W, Bi, Out);
}

// Round 4
// 215.436 us; speedup vs baseline: 1.1347x; 1.0229x over previous
//
#include <hip/hip_runtime.h>

// Problem constants (fixed by the reference)
#define B_TOT   16384
#define N_CAP   32
#define J_CAP   16
#define I_DIM   8
#define D_DIM   16

#define NTH     512          // (n 0..31) x (j 0..15); j = low 4 lane bits
#define NBLK    512
#define BPB     (B_TOT/NBLK) // 32 b per block
#define CHUNK   2            // b per chunk; u lives in regs across softmax
#define NCHUNK  (BPB/CHUNK)  // 16

// DPP exchange-add / exchange-max.
// quad_perm xor1 = 0xB1, quad_perm xor2 = 0x4E,
// row_ror:1/2/4/8 = 0x121/0x122/0x124/0x128 (16-lane rows; ror:8 == xor8)
template<int CTRL>
__device__ __forceinline__ float dpp_xadd(float v) {
    int m = __builtin_amdgcn_update_dpp(0, __float_as_int(v), CTRL, 0xF, 0xF, true);
    return v + __int_as_float(m);
}
template<int CTRL>
__device__ __forceinline__ float dpp_xmax(float v) {
    int m = __builtin_amdgcn_update_dpp(0, __float_as_int(v), CTRL, 0xF, 0xF, true);
    return fmaxf(v, __int_as_float(m));
}
// xor4 within 16-lane group via ds_swizzle (BitMode xor_mask=4, and_mask=0x1F)
__device__ __forceinline__ float swz_xor4(float v) {
    return __int_as_float(__builtin_amdgcn_ds_swizzle(__float_as_int(v), 0x101F));
}

__global__ __launch_bounds__(NTH, 2)
void caps_v4(const float* __restrict__ X,     // (B, J, I)
             const float* __restrict__ Wg,    // (N, J, I, D)
             const float* __restrict__ Bias,  // (N, J, 1)
             float* __restrict__ Out)         // (B, N, D)
{
    // logits/c, double-buffered by chunk parity: [par][cb*544 + n*17 + j]
    __shared__ float sL[2][CHUNK * 544];

    const int t = threadIdx.x;
    const int j = t & 15;

    // ---- W[n,j,:,:] -> 128 VGPRs; t*128 is contiguous & coalesced ----
    float Wr[8][16];
    {
        const float4* wp = reinterpret_cast<const float4*>(Wg + (size_t)t * 128);
        #pragma unroll
        for (int i = 0; i < 8; ++i)
            #pragma unroll
            for (int q = 0; q < 4; ++q) {
                float4 v = wp[i * 4 + q];
                Wr[i][q*4+0] = v.x; Wr[i][q*4+1] = v.y;
                Wr[i][q*4+2] = v.z; Wr[i][q*4+3] = v.w;
            }
    }
    // ANTI-REMAT PIN: asm outputs cannot be rematerialized -> the compiler
    // must keep all 128 W values resident in VGPRs for the whole kernel
    // (R3 counters showed VGPR_Count=100 < 160 live: W loads were being
    // re-issued inside the chunk loop from L2 -> latency-bound, VALUBusy 27%).
    #pragma unroll
    for (int i = 0; i < 8; ++i)
        #pragma unroll
        for (int z = 0; z < 16; ++z)
            asm volatile("" : "+v"(Wr[i][z]));

    // softmax role (threads 0..127): (cb, j, n-quarter)
    const int sm_cb = t >> 6, sm_j = (t >> 2) & 15, sm_nq = t & 3;
    float biasr[8];
    if (t < 128) {
        #pragma unroll
        for (int k = 0; k < 8; ++k)
            biasr[k] = Bias[(sm_nq * 8 + k) * 16 + sm_j];
    }

    const int bblk = blockIdx.x * BPB;

    // x pipeline: preload chunk 0
    float xc[CHUNK][8];
    #pragma unroll
    for (int cb = 0; cb < CHUNK; ++cb) {
        const float4* xp = reinterpret_cast<const float4*>(
            X + (size_t)(bblk + cb) * 128 + j * 8);
        float4 xa = xp[0], xb = xp[1];
        xc[cb][0]=xa.x; xc[cb][1]=xa.y; xc[cb][2]=xa.z; xc[cb][3]=xa.w;
        xc[cb][4]=xb.x; xc[cb][5]=xb.y; xc[cb][6]=xb.z; xc[cb][7]=xb.w;
    }

    #pragma unroll 1
    for (int ch = 0; ch < NCHUNK; ++ch) {
        float* Ls = sL[ch & 1];
        const int b0 = bblk + ch * CHUNK;
        float u[CHUNK][16];

        // ============ phase 1a: u FMAs (consume xc) ============
        #pragma unroll
        for (int cb = 0; cb < CHUNK; ++cb) {
            #pragma unroll
            for (int z = 0; z < 16; ++z) u[cb][z] = xc[cb][0] * Wr[0][z];
            #pragma unroll
            for (int i = 1; i < 8; ++i)
                #pragma unroll
                for (int z = 0; z < 16; ++z)
                    u[cb][z] = fmaf(xc[cb][i], Wr[i][z], u[cb][z]);
        }

        // ============ prefetch next chunk's x (latency hidden by 1b) ============
        {
            const int chn = (ch + 1 < NCHUNK) ? ch + 1 : 0;   // wrap: harmless reload
            const int bn = bblk + chn * CHUNK;
            #pragma unroll
            for (int cb = 0; cb < CHUNK; ++cb) {
                const float4* xp = reinterpret_cast<const float4*>(
                    X + (size_t)(bn + cb) * 128 + j * 8);
                float4 xa = xp[0], xb = xp[1];
                xc[cb][0]=xa.x; xc[cb][1]=xa.y; xc[cb][2]=xa.z; xc[cb][3]=xa.w;
                xc[cb][4]=xb.x; xc[cb][5]=xb.y; xc[cb][6]=xb.z; xc[cb][7]=xb.w;
            }
        }

        // ============ phase 1b: usum allreduce + logits ============
        #pragma unroll
        for (int cb = 0; cb < CHUNK; ++cb) {
            float us[16];
            #pragma unroll
            for (int z = 0; z < 16; ++z) us[z] = dpp_xadd<0x128>(u[cb][z]);
            #pragma unroll
            for (int z = 0; z < 16; ++z) us[z] = dpp_xadd<0x124>(us[z]);
            #pragma unroll
            for (int z = 0; z < 16; ++z) us[z] = dpp_xadd<0x122>(us[z]);
            #pragma unroll
            for (int z = 0; z < 16; ++z) us[z] = dpp_xadd<0x121>(us[z]);

            float lg0 = 0.f, lg1 = 0.f;
            #pragma unroll
            for (int z = 0; z < 8; ++z) {
                lg0 = fmaf(u[cb][z],     us[z],     lg0);
                lg1 = fmaf(u[cb][z + 8], us[z + 8], lg1);
            }
            Ls[cb * 544 + (t >> 4) * 17 + j] = (lg0 + lg1) * 0.25f;  // /sqrt(D)
        }
        __syncthreads();

        // ============ softmax over n (2 waves) ============
        if (t < 128) {
            float* Lb = Ls + sm_cb * 544;
            float l[8];
            #pragma unroll
            for (int k = 0; k < 8; ++k) l[k] = Lb[(sm_nq * 8 + k) * 17 + sm_j];
            float m = l[0];
            #pragma unroll
            for (int k = 1; k < 8; ++k) m = fmaxf(m, l[k]);
            m = dpp_xmax<0xB1>(m);            // allreduce max over the 4 nq lanes
            m = dpp_xmax<0x4E>(m);
            float e[8], Z = 0.f;
            #pragma unroll
            for (int k = 0; k < 8; ++k) { e[k] = __expf(l[k] - m); Z += e[k]; }
            Z = dpp_xadd<0xB1>(Z);
            Z = dpp_xadd<0x4E>(Z);
            const float inv = __builtin_amdgcn_rcpf(Z);
            #pragma unroll
            for (int k = 0; k < 8; ++k)
                Lb[(sm_nq * 8 + k) * 17 + sm_j] = fmaf(e[k], inv, biasr[k]);
        }
        __syncthreads();

        // ============ phase 2: s[b,n,z] = sum_j c * u ============
        #pragma unroll
        for (int cb = 0; cb < CHUNK; ++cb) {
            const float c = Ls[cb * 544 + (t >> 4) * 17 + j];
            float p[16];
            #pragma unroll
            for (int z = 0; z < 16; ++z) p[z] = c * u[cb][z];

            // reduce-scatter over 16 j-lanes; lane j exits with s[z=j]
            float s8[16];
            #pragma unroll
            for (int k = 0; k < 16; ++k) s8[k] = dpp_xadd<0x128>(p[k]);
            float a8[8];
            #pragma unroll
            for (int k = 0; k < 8; ++k) a8[k] = (j & 8) ? s8[k + 8] : s8[k];
            float s2[8];
            #pragma unroll
            for (int k = 0; k < 8; ++k) s2[k] = dpp_xadd<0x4E>(a8[k]);
            float a2[4];
            a2[0] = (j & 2) ? s2[2] : s2[0];
            a2[1] = (j & 2) ? s2[3] : s2[1];
            a2[2] = (j & 2) ? s2[6] : s2[4];
            a2[3] = (j & 2) ? s2[7] : s2[5];
            float s1[4];
            #pragma unroll
            for (int k = 0; k < 4; ++k) s1[k] = dpp_xadd<0xB1>(a2[k]);
            float a1[2];
            a1[0] = (j & 1) ? s1[1] : s1[0];
            a1[1] = (j & 1) ? s1[3] : s1[2];
            float f0 = a1[0] + swz_xor4(a1[0]);
            float f1 = a1[1] + swz_xor4(a1[1]);
            float s = (j & 4) ? f1 : f0;

            Out[(size_t)(b0 + cb) * 512 + t] = s;   // b*512 + n*16 + z, coalesced
        }
    }
}

extern "C" void kernel_launch(void* const* d_in, const int* in_sizes, int n_in,
                              void* d_out, int out_size, void* d_ws, size_t ws_size,
                              hipStream_t stream) {
    const float* X  = (const float*)d_in[0];   // (16384, 16, 8)
    const float* W  = (const float*)d_in[1];   // (32, 16, 8, 16)
    const float* Bi = (const float*)d_in[2];   // (32, 16, 1)
    float* Out = (float*)d_out;                // (16384, 32, 16)

    caps_v4<<<NBLK, NTH, 0, stream>>>(X, W, Bi, Out);
}